// Round 4
// baseline (584.205 us; speedup 1.0000x reference)
//
#include <hip/hip_runtime.h>
#include <math.h>

#define B_ 16
#define S_ 1024
#define D_ 512
#define H_ 4
#define INV_TEMP 0.044194173824159216f   // 1/sqrt(512)
#define C_SCALE 0.00390625f              // 2^-8 range guard for fp16 P
#define OUT_SCALE 256.0f

typedef _Float16 f16;
typedef _Float16 f16x8 __attribute__((ext_vector_type(8)));
typedef _Float16 f16x4 __attribute__((ext_vector_type(4)));
typedef float f32x4 __attribute__((ext_vector_type(4)));

#define AS1(p) ((const __attribute__((address_space(1))) void*)(p))
#define AS3(p) ((__attribute__((address_space(3))) void*)(p))
#define MFMA __builtin_amdgcn_mfma_f32_16x16x32_f16

// ---------------------------------------------------------------------------
// fp32 -> fp16 convert
// ---------------------------------------------------------------------------
__global__ __launch_bounds__(256)
void k_conv(const float* __restrict__ src, f16* __restrict__ dst)
{
    const int i = blockIdx.x * 256 + threadIdx.x;
    const float4 v = ((const float4*)src)[i];
    f16x4 h; h[0] = (f16)v.x; h[1] = (f16)v.y; h[2] = (f16)v.z; h[3] = (f16)v.w;
    ((f16x4*)dst)[i] = h;
}

// ===========================================================================
// k_gemm_v (round-2 proven version): vT = ELU(x @ W^T + b)^T  [B][D][S] fp16
// ===========================================================================
__device__ __forceinline__ void stage128x32(const f16* __restrict__ src, int ld,
                                            char* lds0, int t)
{
    const f16* g0 = src + (size_t)(t >> 2) * ld + (t & 3) * 8;
    __builtin_amdgcn_global_load_lds(AS1(g0), AS3(lds0 + t * 16), 16, 0, 0);
    const f16* g1 = g0 + (size_t)64 * ld;
    __builtin_amdgcn_global_load_lds(AS1(g1), AS3(lds0 + 4096 + t * 16), 16, 0, 0);
}

__device__ __forceinline__ void mma_chunk(const char* ldsA, const char* ldsB,
                                          int wm, int wn, int lr, int quad,
                                          f32x4 (*acc)[4])
{
    f16x8 af[4], bf[4];
#pragma unroll
    for (int i = 0; i < 4; ++i)
        af[i] = *(const f16x8*)(ldsA + ((wm * 64 + i * 16 + lr) * 32 + quad * 8) * 2);
#pragma unroll
    for (int j = 0; j < 4; ++j)
        bf[j] = *(const f16x8*)(ldsB + ((wn * 64 + j * 16 + lr) * 32 + quad * 8) * 2);
#pragma unroll
    for (int i = 0; i < 4; ++i)
#pragma unroll
        for (int j = 0; j < 4; ++j)
            acc[i][j] = MFMA(af[i], bf[j], acc[i][j], 0, 0, 0);
}

__global__ __launch_bounds__(256)
void k_gemm_v(const f16* __restrict__ xh, const f16* __restrict__ Wh,
              const float* __restrict__ bias, f16* __restrict__ vT)
{
    __shared__ __align__(16) char lds[16384];
    const int t = threadIdx.x;
    const int w = t >> 6, lane = t & 63, lr = lane & 15, quad = lane >> 4;
    const int wm = w & 1, wn = w >> 1;
    const int bm = blockIdx.x * 128;   // s rows (16384/128 = 128 blocks)
    const int bn = blockIdx.y * 128;   // e cols (4 blocks)
    f32x4 acc[4][4] = {};
    for (int k0 = 0; k0 < D_; k0 += 32) {
        stage128x32(xh + (size_t)bm * D_ + k0, D_, (char*)lds, t);
        stage128x32(Wh + (size_t)bn * D_ + k0, D_, (char*)lds + 8192, t);
        __syncthreads();
        mma_chunk(lds, lds + 8192, wm, wn, lr, quad, acc);
        __syncthreads();
    }
#pragma unroll
    for (int j = 0; j < 4; ++j) {
        const int e = bn + wn * 64 + j * 16 + lr;
        const float be = bias[e];
#pragma unroll
        for (int i = 0; i < 4; ++i) {
            const int m = bm + wm * 64 + i * 16 + quad * 4;
            const int batch = m >> 10, s = m & 1023;
            f16x4 hv;
#pragma unroll
            for (int r = 0; r < 4; ++r) {
                float z = acc[i][j][r] + be;
                z = (z > 0.0f) ? z : (expf(z) - 1.0f);
                hv[r] = (f16)z;
            }
            *(f16x4*)(vT + ((size_t)batch * D_ + e) * S_ + s) = hv;
        }
    }
}

// ===========================================================================
// k_fused v2: per block = one q-tile of 32 for one batch.
//   kv-chunks of 256; chunks fully below diagonal skipped (pads fixed up).
//   Phase 1: staged GEMM (BK=64, XOR-swizzled LDS) -> masked fp32 scores ->
//            ss accum + fp16 Sc in LDS.
//   Phase 2: barrier-free PV; Sc from LDS, vT frags from global (L2-hot).
//   Epilogue: ss reduce -> inv -> scale, out accumulate, xnext write.
// Grid 512 = 8 XCD * (32 qt * 2 batches); 512 threads; ~58 KiB LDS; 2 blk/CU.
// ===========================================================================
__global__ __launch_bounds__(512, 4)
void k_fused(const f16* __restrict__ xh, const f16* __restrict__ vT,
             const int* __restrict__ etype, f16* __restrict__ xnext,
             float* __restrict__ out, const int accum)
{
    __shared__ __align__(16) f16 xqL[32 * 64];     //  4 KiB (XOR-swizzled)
    __shared__ __align__(16) f16 xkL[256 * 64];    // 32 KiB (XOR-swizzled)
    __shared__ __align__(16) f16 Sc[32 * 264];     // 16.5 KiB (padded stride)
    __shared__ unsigned char padk[1024];
    __shared__ int padidx[32];
    __shared__ int npad;
    __shared__ float spq[32];
    __shared__ float sspad[32];
    __shared__ float ssw[8][32];
    __shared__ float invq[32];

    const int t = threadIdx.x;
    const int wv = t >> 6, lane = t & 63, l15 = lane & 15, quad = lane >> 4;

    // XCD-swizzled block mapping: 2 batches pinned per XCD, heavy qt first
    const int i = blockIdx.x;               // 0..511
    const int j = i >> 3;
    const int b  = (i & 7) * 2 + (j >> 5);  // batch
    const int qt = j & 31;                  // q-tile index
    const int bq = qt * 32;
    const int c0 = qt >> 3;                 // first alive kv-chunk

    const f16* xb  = xh + (size_t)b * S_ * D_;
    const f16* vTb = vT + (size_t)b * D_ * S_;

    // ---- pad scan + init ----
    if (t == 0) npad = 0;
    if (t < 32) sspad[t] = 0.0f;
    __syncthreads();
    {
        const int k1 = t, k2 = t + 512;
        const int e1 = etype[b * S_ + k1], e2 = etype[b * S_ + k2];
        padk[k1] = (e1 == 0); padk[k2] = (e2 == 0);
        if (e1 == 0) { int s = atomicAdd(&npad, 1); if (s < 32) padidx[s] = k1; }
        if (e2 == 0) { int s = atomicAdd(&npad, 1); if (s < 32) padidx[s] = k2; }
    }
    __syncthreads();

    f32x4 oacc[2][4] = {};     // O[q32][e: wv*64 + nt*16 + l15]
    float ssl[2][4] = {};      // per-lane ss partials, q = mt*16+quad*4+r

    for (int kc = c0; kc < 4; ++kc) {
        // -------- phase 1: S-chunk = xq[32][512] . xk[256][512]^T --------
        f32x4 sacc[2][2] = {};
        for (int dc = 0; dc < 8; ++dc) {
            if (t < 256) {                     // xq [32][64], XOR swizzle
                const int row = t >> 3, psl = t & 7, sl = psl ^ (row & 7);
                __builtin_amdgcn_global_load_lds(
                    AS1(xb + (size_t)(bq + row) * D_ + dc * 64 + sl * 8),
                    AS3((char*)xqL + t * 16), 16, 0, 0);
            }
#pragma unroll
            for (int i2 = 0; i2 < 4; ++i2) {   // xk [256][64], XOR swizzle
                const int row = i2 * 64 + (t >> 3), psl = t & 7;
                const int sl = psl ^ (row & 7);
                __builtin_amdgcn_global_load_lds(
                    AS1(xb + (size_t)(kc * 256 + row) * D_ + dc * 64 + sl * 8),
                    AS3((char*)xkL + i2 * 8192 + t * 16), 16, 0, 0);
            }
            __syncthreads();
            f16x8 af[2][2], bf[2][2];
#pragma unroll
            for (int mt = 0; mt < 2; ++mt) {
                const int row = mt * 16 + l15;
#pragma unroll
                for (int ks = 0; ks < 2; ++ks) {
                    const int ch = (ks * 4 + quad) ^ (row & 7);
                    af[mt][ks] = *(const f16x8*)((const char*)xqL + row * 128 + ch * 16);
                }
            }
#pragma unroll
            for (int nt = 0; nt < 2; ++nt) {
                const int row = wv * 32 + nt * 16 + l15;
#pragma unroll
                for (int ks = 0; ks < 2; ++ks) {
                    const int ch = (ks * 4 + quad) ^ (row & 7);
                    bf[nt][ks] = *(const f16x8*)((const char*)xkL + row * 128 + ch * 16);
                }
            }
#pragma unroll
            for (int ks = 0; ks < 2; ++ks)
#pragma unroll
                for (int mt = 0; mt < 2; ++mt)
#pragma unroll
                    for (int nt = 0; nt < 2; ++nt)
                        sacc[mt][nt] = MFMA(af[mt][ks], bf[nt][ks], sacc[mt][nt], 0, 0, 0);
            __syncthreads();
        }
        // mask + ss + Sc write  (D slot: q = mt*16+quad*4+r, kv-col = nt*16+l15)
#pragma unroll
        for (int nt = 0; nt < 2; ++nt) {
            const int klocal = wv * 32 + nt * 16 + l15;
            const int kcol = kc * 256 + klocal;
            const bool pad = padk[kcol] != 0;
#pragma unroll
            for (int mt = 0; mt < 2; ++mt) {
#pragma unroll
                for (int r = 0; r < 4; ++r) {
                    const int q = bq + mt * 16 + quad * 4 + r;
                    float sv = sacc[mt][nt][r] * INV_TEMP;
                    sv = ((kcol > q) || pad) ? sv : 0.0f;
                    ssl[mt][r] += sv * sv;
                    Sc[(mt * 16 + quad * 4 + r) * 264 + klocal] = (f16)(sv * C_SCALE);
                }
            }
        }
        __syncthreads();
        // -------- phase 2: O += Sc[32][256] @ v_chunk  (barrier-free) --------
#pragma unroll 2
        for (int kk = 0; kk < 8; ++kk) {
            f16x8 saf[2], vbf[4];
#pragma unroll
            for (int mt = 0; mt < 2; ++mt)
                saf[mt] = *(const f16x8*)(Sc + (mt * 16 + l15) * 264 + kk * 32 + quad * 8);
#pragma unroll
            for (int nt = 0; nt < 4; ++nt)
                vbf[nt] = *(const f16x8*)(vTb + (size_t)(wv * 64 + nt * 16 + l15) * S_ +
                                          kc * 256 + kk * 32 + quad * 8);
#pragma unroll
            for (int mt = 0; mt < 2; ++mt)
#pragma unroll
                for (int nt = 0; nt < 4; ++nt)
                    oacc[mt][nt] = MFMA(saf[mt], vbf[nt], oacc[mt][nt], 0, 0, 0);
        }
        __syncthreads();
    }

    // ---- exact fixup for pad keys in skipped (dead) chunks ----
    const int np = (npad < 32) ? npad : 32;
    for (int ip = 0; ip < np; ++ip) {
        const int p = padidx[ip];
        if (p >= c0 * 256) continue;   // lives in an alive chunk: already done
        // s_p[q] = dot(x[q], x[p]) * INV_TEMP ; wave wv covers q = wv*4..wv*4+3
        const int qloc = wv * 4 + (lane >> 4);
        float d = 0.0f;
#pragma unroll
        for (int c4 = 0; c4 < 4; ++c4) {
            const f16x8 a = *(const f16x8*)(xb + (size_t)(bq + qloc) * D_ + l15 * 32 + c4 * 8);
            const f16x8 bb = *(const f16x8*)(xb + (size_t)p * D_ + l15 * 32 + c4 * 8);
#pragma unroll
            for (int r = 0; r < 8; ++r) d += (float)a[r] * (float)bb[r];
        }
        d += __shfl_xor(d, 1); d += __shfl_xor(d, 2);
        d += __shfl_xor(d, 4); d += __shfl_xor(d, 8);
        d *= INV_TEMP;
        if (l15 == 0) { spq[qloc] = d; sspad[qloc] += d * d; }
        __syncthreads();
#pragma unroll
        for (int mt = 0; mt < 2; ++mt)
#pragma unroll
            for (int r = 0; r < 4; ++r) {
                const float s = spq[mt * 16 + quad * 4 + r] * C_SCALE;
#pragma unroll
                for (int nt = 0; nt < 4; ++nt) {
                    const int e = wv * 64 + nt * 16 + l15;
                    oacc[mt][nt][r] += s * (float)vTb[(size_t)e * S_ + p];
                }
            }
        __syncthreads();
    }

    // ---- ss reduction -> invq ----
#pragma unroll
    for (int mt = 0; mt < 2; ++mt)
#pragma unroll
        for (int r = 0; r < 4; ++r) {
            float v = ssl[mt][r];
            v += __shfl_xor(v, 1); v += __shfl_xor(v, 2);
            v += __shfl_xor(v, 4); v += __shfl_xor(v, 8);
            if (l15 == 0) ssw[wv][mt * 16 + quad * 4 + r] = v;
        }
    __syncthreads();
    if (t < 32) {
        float s = sspad[t];
#pragma unroll
        for (int w = 0; w < 8; ++w) s += ssw[w][t];
        invq[t] = 1.0f / (C_SCALE * fmaxf(sqrtf(s), 1e-5f));
    }
    __syncthreads();

    // ---- epilogue ----
#pragma unroll
    for (int mt = 0; mt < 2; ++mt)
#pragma unroll
        for (int r = 0; r < 4; ++r) {
            const int q = mt * 16 + quad * 4 + r;
            const float inv = invq[q];
            const size_t rowo = ((size_t)b * S_ + bq + q) * D_;
#pragma unroll
            for (int nt = 0; nt < 4; ++nt) {
                const int e = wv * 64 + nt * 16 + l15;
                const float val = oacc[mt][nt][r] * inv;
                const size_t o = rowo + e;
                out[o] = accum ? (out[o] + val) : val;
                xnext[o] = (f16)val;
            }
        }
}

// ---------------------------------------------------------------------------
// Workspace: X0 @0 (16M), X1 @16M (16M), vT @32M (16M), Wh @48M (2M)
// ---------------------------------------------------------------------------
extern "C" void kernel_launch(void* const* d_in, const int* in_sizes, int n_in,
                              void* d_out, int out_size, void* d_ws, size_t ws_size,
                              hipStream_t stream) {
    const float* x0    = (const float*)d_in[0];
    const int*   etype = (const int*)d_in[2];
    const float* W     = (const float*)d_in[3];
    const float* bias  = (const float*)d_in[4];
    float* out = (float*)d_out;

    char* ws = (char*)d_ws;
    f16* X0 = (f16*)(ws);
    f16* X1 = (f16*)(ws + (16u << 20));
    f16* vT = (f16*)(ws + (32u << 20));
    f16* Wh = (f16*)(ws + (48u << 20));

    k_conv<<<8192, 256, 0, stream>>>(x0, X0);
    k_conv<<<1024, 256, 0, stream>>>(W, Wh);

    const dim3 gridV(128, 4);
    for (int h = 0; h < H_; ++h) {
        f16* Xc = (h & 1) ? X1 : X0;
        f16* Xn = (h & 1) ? X0 : X1;
        k_gemm_v<<<gridV, 256, 0, stream>>>(Xc, Wh + (size_t)h * D_ * D_,
                                            bias + (size_t)h * D_, vT);
        k_fused <<<512, 512, 0, stream>>>(Xc, vT, etype, Xn, out, h > 0);
    }
}